// Round 2
// baseline (602.165 us; speedup 1.0000x reference)
//
#include <hip/hip_runtime.h>
#include <math.h>

#define GN  4
#define MCN 100
#define BN  512
#define INN 456
#define HN  400
#define ON  10

// softplus(s)^2, numerically stable
__device__ __forceinline__ float sp2f(float s) {
    float l = log1pf(__expf(-fabsf(s)));
    float r = fmaxf(s, 0.0f) + l;
    return r * r;
}

// DPP sum across the 16-lane group (lane bits 0-3 = kc). Net:
// xor1, xor2 (quad sums), then ror4 + ror8 complete the 16-sum in every lane.
// All four steps are VALU (v_add_f32_dpp) -- keeps the reduction OFF the LDS pipe.
#define DPP_ADD(v, CTRL) \
    ((v) + __int_as_float(__builtin_amdgcn_update_dpp( \
        0, __float_as_int(v), (CTRL), 0xF, 0xF, true)))

__device__ __forceinline__ float reduce16(float v) {
    v = DPP_ADD(v, 0xB1);    // quad_perm [1,0,3,2]  == xor 1
    v = DPP_ADD(v, 0x4E);    // quad_perm [2,3,0,1]  == xor 2
    v = DPP_ADD(v, 0x124);   // row_ror:4
    v = DPP_ADD(v, 0x128);   // row_ror:8
    return v;
}

// ---------------- kernel 0a: x -> xT, x^2 -> xxT (tiled transpose) ----------------
__global__ __launch_bounds__(256) void k_transpose(
    const float* __restrict__ x, float* __restrict__ xT, float* __restrict__ xxT) {
    __shared__ float tile[64][65];
    int it = blockIdx.x;           // i tile (8 tiles, tail: 456 = 7*64 + 8)
    int bt = blockIdx.y;           // b tile (8 tiles of 64)
    int tx = threadIdx.x & 63;
    int ty = threadIdx.x >> 6;     // 0..3
    int i_in = it * 64 + tx;
    #pragma unroll
    for (int r = 0; r < 16; ++r) {
        int row = r * 4 + ty;
        int b = bt * 64 + row;
        tile[row][tx] = (i_in < INN) ? x[b * INN + i_in] : 0.0f;
    }
    __syncthreads();
    #pragma unroll
    for (int r = 0; r < 16; ++r) {
        int row = r * 4 + ty;
        int i = it * 64 + row;
        if (i < INN) {
            float v = tile[tx][row];           // stride 65 -> conflict-free
            xT[i * BN + bt * 64 + tx]  = v;
            xxT[i * BN + bt * 64 + tx] = v * v;
        }
    }
}

// ---------------- kernel 0b: sp1 = softplus(sigma1)^2, sp3 = softplus(sigma3)^2 ----
__global__ __launch_bounds__(256) void k_sp(
    const float* __restrict__ sigma1, const float* __restrict__ sigma3,
    float* __restrict__ sp1, float* __restrict__ sp3) {
    int idx = blockIdx.x * 256 + threadIdx.x;
    const int n1 = GN * INN * HN / 4;   // 182400 quads
    const int n3 = GN * HN * ON / 4;    // 4000 quads
    if (idx < n1) {
        float4 s = ((const float4*)sigma1)[idx];
        float4 o;
        o.x = sp2f(s.x); o.y = sp2f(s.y); o.z = sp2f(s.z); o.w = sp2f(s.w);
        ((float4*)sp1)[idx] = o;
    } else if (idx < n1 + n3) {
        int k = idx - n1;
        float4 s = ((const float4*)sigma3)[k];
        float4 o;
        o.x = sp2f(s.x); o.y = sp2f(s.y); o.z = sp2f(s.z); o.w = sp2f(s.w);
        ((float4*)sp3)[k] = o;
    }
}

// ---------------- kernel 1: A = x@mu1, S = sqrt((x*x)@sp1) ---------------- (unchanged)
__global__ __launch_bounds__(256) void k_layer1(
    const float* __restrict__ xT, const float* __restrict__ xxT,
    const float* __restrict__ mu1, const float* __restrict__ sp1,
    float* __restrict__ A, float* __restrict__ S) {
    int bt = blockIdx.x;            // 0..31
    int ht = blockIdx.y;            // 0..6
    int g  = blockIdx.z;            // 0..3
    int lane = threadIdx.x & 63;
    int wv   = threadIdx.x >> 6;    // 0..3
    int h = ht * 64 + lane;
    bool hv = h < HN;
    int hc = hv ? h : (HN - 1);     // clamp so masked lanes stay in-bounds
    int b0 = __builtin_amdgcn_readfirstlane(bt * 16 + wv * 4);
    const float* mp = mu1 + (size_t)g * INN * HN + hc;
    const float* pp = sp1 + (size_t)g * INN * HN + hc;
    float accA[4] = {0.f, 0.f, 0.f, 0.f};
    float accD[4] = {0.f, 0.f, 0.f, 0.f};
    #pragma unroll 4
    for (int k = 0; k < INN; ++k) {
        float a = mp[(size_t)k * HN];
        float p = pp[(size_t)k * HN];
        float4 xv  = *(const float4*)(xT  + k * BN + b0);   // wave-uniform 16B
        float4 xxv = *(const float4*)(xxT + k * BN + b0);
        accA[0] = fmaf(a, xv.x,  accA[0]);
        accA[1] = fmaf(a, xv.y,  accA[1]);
        accA[2] = fmaf(a, xv.z,  accA[2]);
        accA[3] = fmaf(a, xv.w,  accA[3]);
        accD[0] = fmaf(p, xxv.x, accD[0]);
        accD[1] = fmaf(p, xxv.y, accD[1]);
        accD[2] = fmaf(p, xxv.z, accD[2]);
        accD[3] = fmaf(p, xxv.w, accD[3]);
    }
    if (hv) {
        #pragma unroll
        for (int j = 0; j < 4; ++j) {
            size_t o = ((size_t)g * BN + (b0 + j)) * HN + h;
            A[o] = accA[j];
            S[o] = sqrtf(accD[j]);
        }
    }
}

// ---------------- kernel 2: layer 2 + softmax + MC mean ----------------
// og split (lane bit 4): og=0 lanes accumulate h*w, og=1 lanes h^2*v.
// acc = 4 rows x 10 = 40 VGPRs -> no spill (verified R1: absmax improved,
// WRITE_SIZE scratch traffic gone).
// R2 changes (latency removal; structure otherwise identical):
//  - depth-2 zeta1 prefetch (za/zb/zn rotation, unroll 2): per-j compute
//    across 4 co-resident waves is ~416cy vs ~900cy HBM latency -> depth-1
//    stalled every iteration; depth-2 gives 832cy of slack.
//  - zeta3 prefetched into registers at chunk START (t<NR lanes, float2
//    loads -- 40B rows are only 8B-aligned), so the barrier-serialized
//    epilogue never waits ~900cy on a cold global load.
template<int NI>
__device__ __forceinline__ void mc_chunk(
    int g, int b, int mb, int kc, int og, int rgg, int t,
    const float* __restrict__ zeta1, const float* __restrict__ zeta3,
    const float* as_s, const float* wp, float* epi, float* psum) {
    const int NR = NI * 8;

    // epilogue zeta3 prefetch: issued here, consumed after the j-loop + reduce
    float z3r[ON];
    if (t < NR) {
        int m = mb + t;
        int mcl = m < MCN ? m : (MCN - 1);
        const float* z3p = zeta3 + ((size_t)(g * MCN + mcl) * BN + b) * ON;
        #pragma unroll
        for (int q = 0; q < 5; ++q) {
            float2 v = *(const float2*)(z3p + 2 * q);
            z3r[2 * q] = v.x; z3r[2 * q + 1] = v.y;
        }
    }

    float acc[NI][ON];
    #pragma unroll
    for (int i = 0; i < NI; ++i)
        #pragma unroll
        for (int o = 0; o < ON; ++o) acc[i][o] = 0.0f;

    const float* zp[NI];
    #pragma unroll
    for (int i = 0; i < NI; ++i) {
        int m = mb + rgg + 8 * i;
        int mcl = m < MCN ? m : (MCN - 1);   // clamp loads; result discarded
        zp[i] = zeta1 + ((size_t)(g * MCN + mcl) * BN + b) * HN + kc;
    }

    // depth-2 zeta pipeline: za = z[j], zb = z[j+1], zn = z[j+2]
    float za[NI], zb[NI];
    #pragma unroll
    for (int i = 0; i < NI; ++i) za[i] = zp[i][0];
    #pragma unroll
    for (int i = 0; i < NI; ++i) zb[i] = zp[i][16];

    #pragma unroll 2
    for (int j = 0; j < 25; ++j) {
        float zn[NI];
        if (j < 23) {
            #pragma unroll
            for (int i = 0; i < NI; ++i) zn[i] = zp[i][16 * (j + 2)];
        } else {
            #pragma unroll
            for (int i = 0; i < NI; ++i) zn[i] = 0.0f;
        }
        float2 as = *(const float2*)(as_s + 2 * (kc + 16 * j));
        const float* wr = wp + j * 160;       // plane row for k = kc + 16*j
        float2 w01 = *(const float2*)(wr);
        float2 w23 = *(const float2*)(wr + 2);
        float2 w45 = *(const float2*)(wr + 4);
        float2 w67 = *(const float2*)(wr + 6);
        float2 w89 = *(const float2*)(wr + 8);
        #pragma unroll
        for (int i = 0; i < NI; ++i) {
            float hv = fmaxf(0.0f, fmaf(as.y, za[i], as.x));
            float c = og ? hv * hv : hv;      // branchless: og=1 lanes use h^2
            acc[i][0] = fmaf(c, w01.x, acc[i][0]);
            acc[i][1] = fmaf(c, w01.y, acc[i][1]);
            acc[i][2] = fmaf(c, w23.x, acc[i][2]);
            acc[i][3] = fmaf(c, w23.y, acc[i][3]);
            acc[i][4] = fmaf(c, w45.x, acc[i][4]);
            acc[i][5] = fmaf(c, w45.y, acc[i][5]);
            acc[i][6] = fmaf(c, w67.x, acc[i][6]);
            acc[i][7] = fmaf(c, w67.y, acc[i][7]);
            acc[i][8] = fmaf(c, w89.x, acc[i][8]);
            acc[i][9] = fmaf(c, w89.y, acc[i][9]);
        }
        #pragma unroll
        for (int i = 0; i < NI; ++i) { za[i] = zb[i]; zb[i] = zn[i]; }
    }

    // reduce across the 16 kc lanes (DPP stays on the VALU pipe)
    #pragma unroll
    for (int i = 0; i < NI; ++i)
        #pragma unroll
        for (int o = 0; o < ON; ++o) acc[i][o] = reduce16(acc[i][o]);

    if (kc == 0) {
        #pragma unroll
        for (int i = 0; i < NI; ++i) {
            int rl = rgg + 8 * i;
            #pragma unroll
            for (int o = 0; o < ON; ++o)
                epi[(rl * ON + o) * 2 + og] = acc[i][o];   // interleave {g,d}
        }
    }
    __syncthreads();

    // epilogue: one thread per MC row of this chunk (zeta3 already in regs)
    if (t < NR) {
        int m = mb + t;
        if (m < MCN) {
            float ov[ON];
            float mx = 0.0f;
            #pragma unroll
            for (int o = 0; o < ON; ++o) {
                float2 gd = *(const float2*)(epi + (t * ON + o) * 2);
                float v = fmaf(sqrtf(gd.y), z3r[o], gd.x);
                v = fmaxf(v, 0.0f);
                ov[o] = v;
                mx = fmaxf(mx, v);
            }
            float se = 0.0f;
            #pragma unroll
            for (int o = 0; o < ON; ++o) { float e = __expf(ov[o] - mx); ov[o] = e; se += e; }
            float r = 1.0f / se;
            #pragma unroll
            for (int o = 0; o < ON; ++o) psum[o] = fmaf(ov[o], r, psum[o]);
        }
    }
    __syncthreads();   // protect epi from next chunk's writers
}

__global__ __launch_bounds__(256, 4) void k_layer2(
    const float* __restrict__ A, const float* __restrict__ S,
    const float* __restrict__ mu3, const float* __restrict__ sp3,
    const float* __restrict__ zeta1, const float* __restrict__ zeta3,
    float* __restrict__ out) {
    int b = blockIdx.x;   // 0..511
    int g = blockIdx.y;   // 0..3

    // Planar weight copies: w_s == mu3[g] layout, v_s == sp3[g] layout.
    // Per-k lane reads: 5 x ds_read_b64 at 40B row stride -> 16 distinct even
    // bank positions; og0/og1 planes alias the same banks (2-way = free).
    __shared__ __align__(16) float w_s[HN * ON];      // 16000 B
    __shared__ __align__(16) float v_s[HN * ON];      // 16000 B
    __shared__ __align__(16) float as_s[2 * HN];      //  3200 B, [h] = {A,S}
    __shared__ __align__(16) float epi[32 * ON * 2];  //  2560 B, [row][o][{g,d}]
    __shared__ __align__(16) float psh[32 * ON];      //  1280 B   (39 KB -> 4 blocks/CU)

    int t = threadIdx.x;

    {   // stage weights: straight float4 copies
        const float4* wsrc = (const float4*)(mu3 + (size_t)g * HN * ON);
        const float4* vsrc = (const float4*)(sp3 + (size_t)g * HN * ON);
        for (int i = t; i < HN * ON / 4; i += 256) {
            ((float4*)w_s)[i] = wsrc[i];
            ((float4*)v_s)[i] = vsrc[i];
        }
    }
    for (int i = t; i < HN; i += 256) {
        size_t src = ((size_t)g * BN + b) * HN + i;
        as_s[2 * i]     = A[src];
        as_s[2 * i + 1] = S[src];
    }
    __syncthreads();

    int kc  = t & 15;
    int og  = (t >> 4) & 1;
    int rgg = t >> 5;            // 0..7

    const float* wp = (og ? v_s : w_s) + kc * ON;

    float psum[ON];
    #pragma unroll
    for (int o = 0; o < ON; ++o) psum[o] = 0.0f;

    #pragma unroll 1
    for (int c = 0; c < 3; ++c)
        mc_chunk<4>(g, b, c * 32, kc, og, rgg, t, zeta1, zeta3, as_s, wp, epi, psum);
    mc_chunk<1>(g, b, 96, kc, og, rgg, t, zeta1, zeta3, as_s, wp, epi, psum);

    if (t < 32) {
        #pragma unroll
        for (int o = 0; o < ON; ++o) psh[t * ON + o] = psum[o];
    }
    __syncthreads();
    if (t < ON) {
        float s = 0.0f;
        #pragma unroll
        for (int r = 0; r < 32; ++r) s += psh[r * ON + t];
        out[b * (GN * ON) + g * ON + t] = s * (1.0f / MCN);   // direct store, no atomics
    }
}

extern "C" void kernel_launch(void* const* d_in, const int* in_sizes, int n_in,
                              void* d_out, int out_size, void* d_ws, size_t ws_size,
                              hipStream_t stream) {
    const float* x      = (const float*)d_in[0];
    const float* mu1    = (const float*)d_in[1];
    const float* sigma1 = (const float*)d_in[2];
    const float* mu3    = (const float*)d_in[3];
    const float* sigma3 = (const float*)d_in[4];
    const float* zeta1  = (const float*)d_in[5];
    const float* zeta3  = (const float*)d_in[6];
    // d_in[7] = num (always 3 -> G = 4, baked into GN)

    float* ws  = (float*)d_ws;
    float* xT  = ws;                       // 456*512
    float* xxT = xT  + INN * BN;           // 456*512
    float* sp1 = xxT + INN * BN;           // 4*456*400
    float* sp3 = sp1 + GN * INN * HN;      // 4*400*10
    float* A   = sp3 + GN * HN * ON;       // 4*512*400
    float* S   = A   + GN * BN * HN;       // 4*512*400
    float* out = (float*)d_out;            // 512*40

    const int nsp = GN * INN * HN / 4 + GN * HN * ON / 4;   // 186400
    k_transpose<<<dim3(8, 8), 256, 0, stream>>>(x, xT, xxT);
    k_sp<<<dim3((nsp + 255) / 256), 256, 0, stream>>>(sigma1, sigma3, sp1, sp3);
    k_layer1<<<dim3(32, 7, GN), 256, 0, stream>>>(xT, xxT, mu1, sp1, A, S);
    k_layer2<<<dim3(BN, GN), 256, 0, stream>>>(A, S, mu3, sp3, zeta1, zeta3, out);
}

// Round 3
// 595.765 us; speedup vs baseline: 1.0107x; 1.0107x over previous
//
#include <hip/hip_runtime.h>
#include <math.h>

#define GN  4
#define MCN 100
#define BN  512
#define INN 456
#define HN  400
#define ON  10

// softplus(s)^2, numerically stable
__device__ __forceinline__ float sp2f(float s) {
    float l = log1pf(__expf(-fabsf(s)));
    float r = fmaxf(s, 0.0f) + l;
    return r * r;
}

// DPP sum across the 16-lane group (lane bits 0-3 = kc). xor1, xor2 (quad
// sums), then ror4 + ror8 complete the 16-sum in every lane. All VALU
// (v_add_f32_dpp) -- keeps the reduction OFF the LDS pipe.
#define DPP_ADD(v, CTRL) \
    ((v) + __int_as_float(__builtin_amdgcn_update_dpp( \
        0, __float_as_int(v), (CTRL), 0xF, 0xF, true)))

__device__ __forceinline__ float reduce16(float v) {
    v = DPP_ADD(v, 0xB1);    // quad_perm [1,0,3,2]  == xor 1
    v = DPP_ADD(v, 0x4E);    // quad_perm [2,3,0,1]  == xor 2
    v = DPP_ADD(v, 0x124);   // row_ror:4
    v = DPP_ADD(v, 0x128);   // row_ror:8
    return v;
}

// ---------------- kernel 0a: x -> xT, x^2 -> xxT (tiled transpose) ----------------
__global__ __launch_bounds__(256) void k_transpose(
    const float* __restrict__ x, float* __restrict__ xT, float* __restrict__ xxT) {
    __shared__ float tile[64][65];
    int it = blockIdx.x;           // i tile (8 tiles, tail: 456 = 7*64 + 8)
    int bt = blockIdx.y;           // b tile (8 tiles of 64)
    int tx = threadIdx.x & 63;
    int ty = threadIdx.x >> 6;     // 0..3
    int i_in = it * 64 + tx;
    #pragma unroll
    for (int r = 0; r < 16; ++r) {
        int row = r * 4 + ty;
        int b = bt * 64 + row;
        tile[row][tx] = (i_in < INN) ? x[b * INN + i_in] : 0.0f;
    }
    __syncthreads();
    #pragma unroll
    for (int r = 0; r < 16; ++r) {
        int row = r * 4 + ty;
        int i = it * 64 + row;
        if (i < INN) {
            float v = tile[tx][row];           // stride 65 -> conflict-free
            xT[i * BN + bt * 64 + tx]  = v;
            xxT[i * BN + bt * 64 + tx] = v * v;
        }
    }
}

// ---------------- kernel 0b: sp1 = softplus(sigma1)^2, sp3 = softplus(sigma3)^2 ----
__global__ __launch_bounds__(256) void k_sp(
    const float* __restrict__ sigma1, const float* __restrict__ sigma3,
    float* __restrict__ sp1, float* __restrict__ sp3) {
    int idx = blockIdx.x * 256 + threadIdx.x;
    const int n1 = GN * INN * HN / 4;   // 182400 quads
    const int n3 = GN * HN * ON / 4;    // 4000 quads
    if (idx < n1) {
        float4 s = ((const float4*)sigma1)[idx];
        float4 o;
        o.x = sp2f(s.x); o.y = sp2f(s.y); o.z = sp2f(s.z); o.w = sp2f(s.w);
        ((float4*)sp1)[idx] = o;
    } else if (idx < n1 + n3) {
        int k = idx - n1;
        float4 s = ((const float4*)sigma3)[k];
        float4 o;
        o.x = sp2f(s.x); o.y = sp2f(s.y); o.z = sp2f(s.z); o.w = sp2f(s.w);
        ((float4*)sp3)[k] = o;
    }
}

// ---------------- kernel 1: A = x@mu1, S = sqrt((x*x)@sp1) ---------------- (unchanged)
__global__ __launch_bounds__(256) void k_layer1(
    const float* __restrict__ xT, const float* __restrict__ xxT,
    const float* __restrict__ mu1, const float* __restrict__ sp1,
    float* __restrict__ A, float* __restrict__ S) {
    int bt = blockIdx.x;            // 0..31
    int ht = blockIdx.y;            // 0..6
    int g  = blockIdx.z;            // 0..3
    int lane = threadIdx.x & 63;
    int wv   = threadIdx.x >> 6;    // 0..3
    int h = ht * 64 + lane;
    bool hv = h < HN;
    int hc = hv ? h : (HN - 1);     // clamp so masked lanes stay in-bounds
    int b0 = __builtin_amdgcn_readfirstlane(bt * 16 + wv * 4);
    const float* mp = mu1 + (size_t)g * INN * HN + hc;
    const float* pp = sp1 + (size_t)g * INN * HN + hc;
    float accA[4] = {0.f, 0.f, 0.f, 0.f};
    float accD[4] = {0.f, 0.f, 0.f, 0.f};
    #pragma unroll 4
    for (int k = 0; k < INN; ++k) {
        float a = mp[(size_t)k * HN];
        float p = pp[(size_t)k * HN];
        float4 xv  = *(const float4*)(xT  + k * BN + b0);   // wave-uniform 16B
        float4 xxv = *(const float4*)(xxT + k * BN + b0);
        accA[0] = fmaf(a, xv.x,  accA[0]);
        accA[1] = fmaf(a, xv.y,  accA[1]);
        accA[2] = fmaf(a, xv.z,  accA[2]);
        accA[3] = fmaf(a, xv.w,  accA[3]);
        accD[0] = fmaf(p, xxv.x, accD[0]);
        accD[1] = fmaf(p, xxv.y, accD[1]);
        accD[2] = fmaf(p, xxv.z, accD[2]);
        accD[3] = fmaf(p, xxv.w, accD[3]);
    }
    if (hv) {
        #pragma unroll
        for (int j = 0; j < 4; ++j) {
            size_t o = ((size_t)g * BN + (b0 + j)) * HN + h;
            A[o] = accA[j];
            S[o] = sqrtf(accD[j]);
        }
    }
}

// ---------------- kernel 2: layer 2 + softmax + MC mean ----------------
// R3: occupancy attack. R2 showed VALUBusy 37% / HBM 22% / LDS ~30% with
// Occupancy 42% -- latency-bound, capped by LDS at 4 blk/CU x 4 waves = 50%.
// Changes:
//  - 512-thread blocks (one (b,g) each): rows split across 16 rg groups.
//    Chunks: NI=4 (rows 0-63) + NI=3 (rows 64-111, 100+ clamped).
//  - __launch_bounds__(512, 8): forces VGPR<=64 (the 64-reg schedule for this
//    exact loop body was already proven by R2's compile) -> 8 waves/SIMD.
//  - psh overlaid on epi -> LDS 40320 B -> 4 blocks/CU -> 32 waves/CU (100% cap,
//    2x R2). TLP now hides the LDS+HBM latency that per-wave ILP (R2) couldn't.
//  - reverted depth-2 / z3r prefetch (reg pressure at the forced 64 bound).
// Lane map: t = [rgg(4b) | og(1b) | kc(4b)]; og=0 lanes accumulate h*w,
// og=1 lanes h^2*v (acc = NI x 10 <= 40 VGPRs). Weight ds_read pattern is
// unchanged -> broadcasts + 2-way aliasing only (R2 measured 0 conflicts).
template<int NI>
__device__ __forceinline__ void mc_chunk(
    int g, int b, int mb, int kc, int og, int rgg, int t,
    const float* __restrict__ zeta1, const float* __restrict__ zeta3,
    const float* as_s, const float* wp, float* epi, float* psum) {
    const int NR = NI * 16;     // rows in this chunk

    float acc[NI][ON];
    #pragma unroll
    for (int i = 0; i < NI; ++i)
        #pragma unroll
        for (int o = 0; o < ON; ++o) acc[i][o] = 0.0f;

    const float* zp[NI];
    #pragma unroll
    for (int i = 0; i < NI; ++i) {
        int m = mb + rgg + 16 * i;
        int mcl = m < MCN ? m : (MCN - 1);   // clamp loads; result discarded
        zp[i] = zeta1 + ((size_t)(g * MCN + mcl) * BN + b) * HN + kc;
    }

    // depth-1 zeta prefetch
    float zc[NI];
    #pragma unroll
    for (int i = 0; i < NI; ++i) zc[i] = zp[i][0];

    #pragma unroll 1
    for (int j = 0; j < 25; ++j) {
        float zn[NI];
        if (j < 24) {
            #pragma unroll
            for (int i = 0; i < NI; ++i) zn[i] = zp[i][16 * (j + 1)];
        } else {
            #pragma unroll
            for (int i = 0; i < NI; ++i) zn[i] = 0.0f;
        }
        float2 as = *(const float2*)(as_s + 2 * (kc + 16 * j));
        const float* wr = wp + j * 160;       // plane row for k = kc + 16*j
        float2 w01 = *(const float2*)(wr);
        float2 w23 = *(const float2*)(wr + 2);
        float2 w45 = *(const float2*)(wr + 4);
        float2 w67 = *(const float2*)(wr + 6);
        float2 w89 = *(const float2*)(wr + 8);
        #pragma unroll
        for (int i = 0; i < NI; ++i) {
            float hv = fmaxf(0.0f, fmaf(as.y, zc[i], as.x));
            float c = og ? hv * hv : hv;      // branchless: og=1 lanes use h^2
            acc[i][0] = fmaf(c, w01.x, acc[i][0]);
            acc[i][1] = fmaf(c, w01.y, acc[i][1]);
            acc[i][2] = fmaf(c, w23.x, acc[i][2]);
            acc[i][3] = fmaf(c, w23.y, acc[i][3]);
            acc[i][4] = fmaf(c, w45.x, acc[i][4]);
            acc[i][5] = fmaf(c, w45.y, acc[i][5]);
            acc[i][6] = fmaf(c, w67.x, acc[i][6]);
            acc[i][7] = fmaf(c, w67.y, acc[i][7]);
            acc[i][8] = fmaf(c, w89.x, acc[i][8]);
            acc[i][9] = fmaf(c, w89.y, acc[i][9]);
        }
        #pragma unroll
        for (int i = 0; i < NI; ++i) zc[i] = zn[i];
    }

    // reduce across the 16 kc lanes (DPP stays on the VALU pipe)
    #pragma unroll
    for (int i = 0; i < NI; ++i)
        #pragma unroll
        for (int o = 0; o < ON; ++o) acc[i][o] = reduce16(acc[i][o]);

    if (kc == 0) {
        #pragma unroll
        for (int i = 0; i < NI; ++i) {
            int rl = rgg + 16 * i;           // 0..63
            #pragma unroll
            for (int o = 0; o < ON; ++o)
                epi[(rl * ON + o) * 2 + og] = acc[i][o];   // interleave {g,d}
        }
    }
    __syncthreads();

    // epilogue: one thread per MC row of this chunk
    if (t < NR) {
        int m = mb + t;
        if (m < MCN) {
            const float* z3p = zeta3 + ((size_t)(g * MCN + m) * BN + b) * ON;
            float ov[ON];
            float mx = 0.0f;
            #pragma unroll
            for (int o = 0; o < ON; ++o) {
                float2 gd = *(const float2*)(epi + (t * ON + o) * 2);
                float v = fmaf(sqrtf(gd.y), z3p[o], gd.x);
                v = fmaxf(v, 0.0f);
                ov[o] = v;
                mx = fmaxf(mx, v);
            }
            float se = 0.0f;
            #pragma unroll
            for (int o = 0; o < ON; ++o) { float e = __expf(ov[o] - mx); ov[o] = e; se += e; }
            float r = 1.0f / se;
            #pragma unroll
            for (int o = 0; o < ON; ++o) psum[o] = fmaf(ov[o], r, psum[o]);
        }
    }
    __syncthreads();   // protect epi from next chunk's writers
}

__global__ __launch_bounds__(512, 8) void k_layer2(
    const float* __restrict__ A, const float* __restrict__ S,
    const float* __restrict__ mu3, const float* __restrict__ sp3,
    const float* __restrict__ zeta1, const float* __restrict__ zeta3,
    float* __restrict__ out) {
    int b = blockIdx.x;   // 0..511
    int g = blockIdx.y;   // 0..3

    // Planar weight copies: w_s == mu3[g] layout, v_s == sp3[g] layout.
    // Per-k lane reads: 5 x ds_read_b64 at 40B row stride -> 16 distinct even
    // bank positions; og0/og1 planes alias the same banks (2-way = free).
    // LDS budget: 16000+16000+3200+5120 = 40320 B (+runtime pad ~384) <= 40960
    // -> 4 blocks/CU at 8 waves each = 32 waves/CU.
    __shared__ __align__(16) float w_s[HN * ON];      // 16000 B
    __shared__ __align__(16) float v_s[HN * ON];      // 16000 B
    __shared__ __align__(16) float as_s[2 * HN];      //  3200 B, [h] = {A,S}
    __shared__ __align__(16) float epi[64 * ON * 2];  //  5120 B, [row][o][{g,d}]
                                                      //  (reused as psh at the end)
    int t = threadIdx.x;

    {   // stage weights: straight float4 copies
        const float4* wsrc = (const float4*)(mu3 + (size_t)g * HN * ON);
        const float4* vsrc = (const float4*)(sp3 + (size_t)g * HN * ON);
        for (int i = t; i < HN * ON / 4; i += 512) {
            ((float4*)w_s)[i] = wsrc[i];
            ((float4*)v_s)[i] = vsrc[i];
        }
    }
    if (t < HN) {
        size_t src = ((size_t)g * BN + b) * HN + t;
        as_s[2 * t]     = A[src];
        as_s[2 * t + 1] = S[src];
    }
    __syncthreads();

    int kc  = t & 15;
    int og  = (t >> 4) & 1;
    int rgg = t >> 5;            // 0..15

    const float* wp = (og ? v_s : w_s) + kc * ON;

    float psum[ON];
    #pragma unroll
    for (int o = 0; o < ON; ++o) psum[o] = 0.0f;

    mc_chunk<4>(g, b,  0, kc, og, rgg, t, zeta1, zeta3, as_s, wp, epi, psum);
    mc_chunk<3>(g, b, 64, kc, og, rgg, t, zeta1, zeta3, as_s, wp, epi, psum);

    // final reduction: threads t<64 hold psums of rows {t, 64+t}; overlay epi
    if (t < 64) {
        #pragma unroll
        for (int o = 0; o < ON; ++o) epi[t * ON + o] = psum[o];
    }
    __syncthreads();
    if (t < ON) {
        float s = 0.0f;
        #pragma unroll
        for (int r = 0; r < 64; ++r) s += epi[r * ON + t];
        out[b * (GN * ON) + g * ON + t] = s * (1.0f / MCN);   // direct store
    }
}

extern "C" void kernel_launch(void* const* d_in, const int* in_sizes, int n_in,
                              void* d_out, int out_size, void* d_ws, size_t ws_size,
                              hipStream_t stream) {
    const float* x      = (const float*)d_in[0];
    const float* mu1    = (const float*)d_in[1];
    const float* sigma1 = (const float*)d_in[2];
    const float* mu3    = (const float*)d_in[3];
    const float* sigma3 = (const float*)d_in[4];
    const float* zeta1  = (const float*)d_in[5];
    const float* zeta3  = (const float*)d_in[6];
    // d_in[7] = num (always 3 -> G = 4, baked into GN)

    float* ws  = (float*)d_ws;
    float* xT  = ws;                       // 456*512
    float* xxT = xT  + INN * BN;           // 456*512
    float* sp1 = xxT + INN * BN;           // 4*456*400
    float* sp3 = sp1 + GN * INN * HN;      // 4*400*10
    float* A   = sp3 + GN * HN * ON;       // 4*512*400
    float* S   = A   + GN * BN * HN;       // 4*512*400
    float* out = (float*)d_out;            // 512*40

    const int nsp = GN * INN * HN / 4 + GN * HN * ON / 4;   // 186400
    k_transpose<<<dim3(8, 8), 256, 0, stream>>>(x, xT, xxT);
    k_sp<<<dim3((nsp + 255) / 256), 256, 0, stream>>>(sigma1, sigma3, sp1, sp3);
    k_layer1<<<dim3(32, 7, GN), 256, 0, stream>>>(xT, xxT, mu1, sp1, A, S);
    k_layer2<<<dim3(BN, GN), 512, 0, stream>>>(A, S, mu3, sp3, zeta1, zeta3, out);
}

// Round 4
// 565.857 us; speedup vs baseline: 1.0642x; 1.0529x over previous
//
#include <hip/hip_runtime.h>
#include <math.h>

#define GN  4
#define MCN 100
#define BN  512
#define INN 456
#define HN  400
#define ON  10

// softplus(s)^2, numerically stable
__device__ __forceinline__ float sp2f(float s) {
    float l = log1pf(__expf(-fabsf(s)));
    float r = fmaxf(s, 0.0f) + l;
    return r * r;
}

// DPP sum across the 16-lane group (lane bits 0-3 = kc). xor1, xor2 (quad
// sums), then ror4 + ror8 complete the 16-sum in every lane. All VALU
// (v_add_f32_dpp) -- keeps the reduction OFF the LDS pipe.
#define DPP_ADD(v, CTRL) \
    ((v) + __int_as_float(__builtin_amdgcn_update_dpp( \
        0, __float_as_int(v), (CTRL), 0xF, 0xF, true)))

__device__ __forceinline__ float reduce16(float v) {
    v = DPP_ADD(v, 0xB1);    // quad_perm [1,0,3,2]  == xor 1
    v = DPP_ADD(v, 0x4E);    // quad_perm [2,3,0,1]  == xor 2
    v = DPP_ADD(v, 0x124);   // row_ror:4
    v = DPP_ADD(v, 0x128);   // row_ror:8
    return v;
}

// ---------------- kernel 0a: x -> xT, x^2 -> xxT (tiled transpose) ----------------
__global__ __launch_bounds__(256) void k_transpose(
    const float* __restrict__ x, float* __restrict__ xT, float* __restrict__ xxT) {
    __shared__ float tile[64][65];
    int it = blockIdx.x;           // i tile (8 tiles, tail: 456 = 7*64 + 8)
    int bt = blockIdx.y;           // b tile (8 tiles of 64)
    int tx = threadIdx.x & 63;
    int ty = threadIdx.x >> 6;     // 0..3
    int i_in = it * 64 + tx;
    #pragma unroll
    for (int r = 0; r < 16; ++r) {
        int row = r * 4 + ty;
        int b = bt * 64 + row;
        tile[row][tx] = (i_in < INN) ? x[b * INN + i_in] : 0.0f;
    }
    __syncthreads();
    #pragma unroll
    for (int r = 0; r < 16; ++r) {
        int row = r * 4 + ty;
        int i = it * 64 + row;
        if (i < INN) {
            float v = tile[tx][row];           // stride 65 -> conflict-free
            xT[i * BN + bt * 64 + tx]  = v;
            xxT[i * BN + bt * 64 + tx] = v * v;
        }
    }
}

// ---------------- kernel 0b: sp1 = softplus(sigma1)^2, sp3 = softplus(sigma3)^2 ----
__global__ __launch_bounds__(256) void k_sp(
    const float* __restrict__ sigma1, const float* __restrict__ sigma3,
    float* __restrict__ sp1, float* __restrict__ sp3) {
    int idx = blockIdx.x * 256 + threadIdx.x;
    const int n1 = GN * INN * HN / 4;   // 182400 quads
    const int n3 = GN * HN * ON / 4;    // 4000 quads
    if (idx < n1) {
        float4 s = ((const float4*)sigma1)[idx];
        float4 o;
        o.x = sp2f(s.x); o.y = sp2f(s.y); o.z = sp2f(s.z); o.w = sp2f(s.w);
        ((float4*)sp1)[idx] = o;
    } else if (idx < n1 + n3) {
        int k = idx - n1;
        float4 s = ((const float4*)sigma3)[k];
        float4 o;
        o.x = sp2f(s.x); o.y = sp2f(s.y); o.z = sp2f(s.z); o.w = sp2f(s.w);
        ((float4*)sp3)[k] = o;
    }
}

// ---------------- kernel 1: A = x@mu1, S = sqrt((x*x)@sp1) ---------------- (unchanged)
__global__ __launch_bounds__(256) void k_layer1(
    const float* __restrict__ xT, const float* __restrict__ xxT,
    const float* __restrict__ mu1, const float* __restrict__ sp1,
    float* __restrict__ A, float* __restrict__ S) {
    int bt = blockIdx.x;            // 0..31
    int ht = blockIdx.y;            // 0..6
    int g  = blockIdx.z;            // 0..3
    int lane = threadIdx.x & 63;
    int wv   = threadIdx.x >> 6;    // 0..3
    int h = ht * 64 + lane;
    bool hv = h < HN;
    int hc = hv ? h : (HN - 1);     // clamp so masked lanes stay in-bounds
    int b0 = __builtin_amdgcn_readfirstlane(bt * 16 + wv * 4);
    const float* mp = mu1 + (size_t)g * INN * HN + hc;
    const float* pp = sp1 + (size_t)g * INN * HN + hc;
    float accA[4] = {0.f, 0.f, 0.f, 0.f};
    float accD[4] = {0.f, 0.f, 0.f, 0.f};
    #pragma unroll 4
    for (int k = 0; k < INN; ++k) {
        float a = mp[(size_t)k * HN];
        float p = pp[(size_t)k * HN];
        float4 xv  = *(const float4*)(xT  + k * BN + b0);   // wave-uniform 16B
        float4 xxv = *(const float4*)(xxT + k * BN + b0);
        accA[0] = fmaf(a, xv.x,  accA[0]);
        accA[1] = fmaf(a, xv.y,  accA[1]);
        accA[2] = fmaf(a, xv.z,  accA[2]);
        accA[3] = fmaf(a, xv.w,  accA[3]);
        accD[0] = fmaf(p, xxv.x, accD[0]);
        accD[1] = fmaf(p, xxv.y, accD[1]);
        accD[2] = fmaf(p, xxv.z, accD[2]);
        accD[3] = fmaf(p, xxv.w, accD[3]);
    }
    if (hv) {
        #pragma unroll
        for (int j = 0; j < 4; ++j) {
            size_t o = ((size_t)g * BN + (b0 + j)) * HN + h;
            A[o] = accA[j];
            S[o] = sqrtf(accD[j]);
        }
    }
}

// ---------------- kernel 2: layer 2 + softmax + MC mean ----------------
// R4: zeta1 stream vectorization. R1-R3 showed the kernel is stalled in a way
// neither ILP (R2) nor 2x occupancy (R3) fixes; the shared trait is scalar
// 4B/lane zeta1 loads at stride 64B -> ~10k concurrent fine-grain HBM streams.
// New k-loop: each thread owns k = 4*kc + 64*j (+16-wide tail), so zeta1 is
// global_load_dwordx4 (256B contiguous per 16-lane group, 4x fewer VMEM instrs,
// 4x fewer streams). Weights in TRANSPOSED LDS layout wT[o][k] -> per-j2 thread
// reads 10 x ds_read_b128 (4 k-rows at once, half the LDS instrs per k; ~4-way
// bank aliasing = 1.58x, acceptable). Row/epilogue structure = R1 (best: 182us).
// Lane map: t = [rgg(3b) | og(1b) | kc(4b)]; og=0 -> h*w, og=1 -> h^2*v.
template<int NI>
__device__ __forceinline__ void mc_chunk(
    int g, int b, int mb, int kc, int og, int rgg, int t,
    const float* __restrict__ zeta1, const float* __restrict__ zeta3,
    const float* as_s, const float* wp, float* epi, float* psum) {
    const int NR = NI * 8;

    float acc[NI][ON];
    #pragma unroll
    for (int i = 0; i < NI; ++i)
        #pragma unroll
        for (int o = 0; o < ON; ++o) acc[i][o] = 0.0f;

    const float* zp[NI];
    #pragma unroll
    for (int i = 0; i < NI; ++i) {
        int m = mb + rgg + 8 * i;
        int mcl = m < MCN ? m : (MCN - 1);   // clamp loads; result discarded
        zp[i] = zeta1 + ((size_t)(g * MCN + mcl) * BN + b) * HN + 4 * kc;
    }

    // depth-1 float4 zeta pipeline (each load covers 4 k)
    float4 zc[NI];
    #pragma unroll
    for (int i = 0; i < NI; ++i) zc[i] = *(const float4*)(zp[i]);

    #pragma unroll 1
    for (int j = 0; j < 6; ++j) {
        float4 zn[NI];
        if (j < 5) {
            #pragma unroll
            for (int i = 0; i < NI; ++i) zn[i] = *(const float4*)(zp[i] + 64 * (j + 1));
        } else {
            #pragma unroll
            for (int i = 0; i < NI; ++i) zn[i] = zc[i];   // dummy
        }
        int k0 = 4 * kc + 64 * j;
        // A,S for k0..k0+3: 8 consecutive floats (16B-aligned)
        float4 as01 = *(const float4*)(as_s + 2 * k0);       // A0 S0 A1 S1
        float4 as23 = *(const float4*)(as_s + 2 * k0 + 4);   // A2 S2 A3 S3
        // weights: 10 rows x 4 consecutive k (b128 each)
        float4 W[ON];
        #pragma unroll
        for (int o = 0; o < ON; ++o) W[o] = *(const float4*)(wp + o * HN + k0);
        #pragma unroll
        for (int i = 0; i < NI; ++i) {
            float h0 = fmaxf(0.0f, fmaf(as01.y, zc[i].x, as01.x));
            float h1 = fmaxf(0.0f, fmaf(as01.w, zc[i].y, as01.z));
            float h2 = fmaxf(0.0f, fmaf(as23.y, zc[i].z, as23.x));
            float h3 = fmaxf(0.0f, fmaf(as23.w, zc[i].w, as23.z));
            float c0 = og ? h0 * h0 : h0;    // branchless og select
            float c1 = og ? h1 * h1 : h1;
            float c2 = og ? h2 * h2 : h2;
            float c3 = og ? h3 * h3 : h3;
            #pragma unroll
            for (int o = 0; o < ON; ++o) {
                acc[i][o] = fmaf(c0, W[o].x, acc[i][o]);
                acc[i][o] = fmaf(c1, W[o].y, acc[i][o]);
                acc[i][o] = fmaf(c2, W[o].z, acc[i][o]);
                acc[i][o] = fmaf(c3, W[o].w, acc[i][o]);
            }
        }
        #pragma unroll
        for (int i = 0; i < NI; ++i) zc[i] = zn[i];
    }

    // tail: k = 384 + kc (16 k across the kc lanes)
    {
        int k = 384 + kc;
        int toff = 384 - 3 * kc;             // zp is row + 4*kc; want row + 384 + kc
        float2 as = *(const float2*)(as_s + 2 * k);
        float wt[ON];
        #pragma unroll
        for (int o = 0; o < ON; ++o) wt[o] = wp[o * HN + k];
        #pragma unroll
        for (int i = 0; i < NI; ++i) {
            float z = zp[i][toff];
            float hv = fmaxf(0.0f, fmaf(as.y, z, as.x));
            float c = og ? hv * hv : hv;
            #pragma unroll
            for (int o = 0; o < ON; ++o) acc[i][o] = fmaf(c, wt[o], acc[i][o]);
        }
    }

    // reduce across the 16 kc lanes (DPP stays on the VALU pipe)
    #pragma unroll
    for (int i = 0; i < NI; ++i)
        #pragma unroll
        for (int o = 0; o < ON; ++o) acc[i][o] = reduce16(acc[i][o]);

    if (kc == 0) {
        #pragma unroll
        for (int i = 0; i < NI; ++i) {
            int rl = rgg + 8 * i;
            #pragma unroll
            for (int o = 0; o < ON; ++o)
                epi[(rl * ON + o) * 2 + og] = acc[i][o];   // interleave {g,d}
        }
    }
    __syncthreads();

    // epilogue: one thread per MC row of this chunk
    if (t < NR) {
        int m = mb + t;
        if (m < MCN) {
            const float* z3p = zeta3 + ((size_t)(g * MCN + m) * BN + b) * ON;
            float ov[ON];
            float mx = 0.0f;
            #pragma unroll
            for (int o = 0; o < ON; ++o) {
                float2 gd = *(const float2*)(epi + (t * ON + o) * 2);
                float v = fmaf(sqrtf(gd.y), z3p[o], gd.x);
                v = fmaxf(v, 0.0f);
                ov[o] = v;
                mx = fmaxf(mx, v);
            }
            float se = 0.0f;
            #pragma unroll
            for (int o = 0; o < ON; ++o) { float e = __expf(ov[o] - mx); ov[o] = e; se += e; }
            float r = 1.0f / se;
            #pragma unroll
            for (int o = 0; o < ON; ++o) psum[o] = fmaf(ov[o], r, psum[o]);
        }
    }
    __syncthreads();   // protect epi from next chunk's writers
}

__global__ __launch_bounds__(256, 3) void k_layer2(
    const float* __restrict__ A, const float* __restrict__ S,
    const float* __restrict__ mu3, const float* __restrict__ sp3,
    const float* __restrict__ zeta1, const float* __restrict__ zeta3,
    float* __restrict__ out) {
    int b = blockIdx.x;   // 0..511
    int g = blockIdx.y;   // 0..3

    // Transposed weight planes: wT[o][h] = mu3[g][h][o], vT[o][h] = sp3[g][h][o].
    // Per-j2 lane reads: 10 b128 at base bank 4kc mod 32 -> 2-way among kc
    // lanes (free) x 2-way og (different addr, same banks) = ~4-way (1.58x).
    // LDS: 4000+4000+800+640+320 floats = 39040 B -> 4 blocks/CU.
    __shared__ __align__(16) float wT_s[ON * HN];     // 16000 B
    __shared__ __align__(16) float vT_s[ON * HN];     // 16000 B
    __shared__ __align__(16) float as_s[2 * HN];      //  3200 B, [k] = {A,S}
    __shared__ __align__(16) float epi[32 * ON * 2];  //  2560 B, [row][o][{g,d}]
    __shared__ __align__(16) float psh[32 * ON];      //  1280 B

    int t = threadIdx.x;

    {   // stage weights transposed (h-major global -> o-major LDS)
        const float* wsrc = mu3 + (size_t)g * HN * ON;
        const float* vsrc = sp3 + (size_t)g * HN * ON;
        for (int i = t; i < HN * ON; i += 256) {
            int h = i / ON, o = i - h * ON;
            wT_s[o * HN + h] = wsrc[i];
            vT_s[o * HN + h] = vsrc[i];
        }
    }
    for (int i = t; i < HN; i += 256) {
        size_t src = ((size_t)g * BN + b) * HN + i;
        as_s[2 * i]     = A[src];
        as_s[2 * i + 1] = S[src];
    }
    __syncthreads();

    int kc  = t & 15;
    int og  = (t >> 4) & 1;
    int rgg = t >> 5;            // 0..7

    const float* wp = og ? vT_s : wT_s;

    float psum[ON];
    #pragma unroll
    for (int o = 0; o < ON; ++o) psum[o] = 0.0f;

    #pragma unroll 1
    for (int c = 0; c < 3; ++c)
        mc_chunk<4>(g, b, c * 32, kc, og, rgg, t, zeta1, zeta3, as_s, wp, epi, psum);
    mc_chunk<1>(g, b, 96, kc, og, rgg, t, zeta1, zeta3, as_s, wp, epi, psum);

    if (t < 32) {
        #pragma unroll
        for (int o = 0; o < ON; ++o) psh[t * ON + o] = psum[o];
    }
    __syncthreads();
    if (t < ON) {
        float s = 0.0f;
        #pragma unroll
        for (int r = 0; r < 32; ++r) s += psh[r * ON + t];
        out[b * (GN * ON) + g * ON + t] = s * (1.0f / MCN);   // direct store
    }
}

extern "C" void kernel_launch(void* const* d_in, const int* in_sizes, int n_in,
                              void* d_out, int out_size, void* d_ws, size_t ws_size,
                              hipStream_t stream) {
    const float* x      = (const float*)d_in[0];
    const float* mu1    = (const float*)d_in[1];
    const float* sigma1 = (const float*)d_in[2];
    const float* mu3    = (const float*)d_in[3];
    const float* sigma3 = (const float*)d_in[4];
    const float* zeta1  = (const float*)d_in[5];
    const float* zeta3  = (const float*)d_in[6];
    // d_in[7] = num (always 3 -> G = 4, baked into GN)

    float* ws  = (float*)d_ws;
    float* xT  = ws;                       // 456*512
    float* xxT = xT  + INN * BN;           // 456*512
    float* sp1 = xxT + INN * BN;           // 4*456*400
    float* sp3 = sp1 + GN * INN * HN;      // 4*400*10
    float* A   = sp3 + GN * HN * ON;       // 4*512*400
    float* S   = A   + GN * BN * HN;       // 4*512*400
    float* out = (float*)d_out;            // 512*40

    const int nsp = GN * INN * HN / 4 + GN * HN * ON / 4;   // 186400
    k_transpose<<<dim3(8, 8), 256, 0, stream>>>(x, xT, xxT);
    k_sp<<<dim3((nsp + 255) / 256), 256, 0, stream>>>(sigma1, sigma3, sp1, sp3);
    k_layer1<<<dim3(32, 7, GN), 256, 0, stream>>>(xT, xxT, mu1, sp1, A, S);
    k_layer2<<<dim3(BN, GN), 256, 0, stream>>>(A, S, mu3, sp3, zeta1, zeta3, out);
}